// Round 5
// baseline (303.127 us; speedup 1.0000x reference)
//
#include <hip/hip_runtime.h>
#include <cstddef>

#define B_ 32
#define C_ 32
#define L_ 16384
#define H_ 4
#define DH_ 8
#define NB_ 3
#define DOUT_ 10
#define SEG_ 512
#define S_ (L_/SEG_)   // 32 segments per (b,head)

#define WTILE 512  // positions per WG (2 sub-tiles of 256)
#define AST  40    // A_lds row stride (halfs): 80 B/row -> 16B-aligned b128 frag reads

typedef _Float16 f16_t;
typedef _Float16 f16x2 __attribute__((ext_vector_type(2)));
typedef _Float16 f16x8 __attribute__((ext_vector_type(8)));
typedef float    f32x4 __attribute__((ext_vector_type(4)));

// Branch-free gelu via Abramowitz-Stegun 7.1.26 erf approximation (|eps|<=1.5e-7).
__device__ __forceinline__ float gelu_f(float x){
    const float z  = fabsf(x) * 0.70710678118654752440f;
    const float t  = __builtin_amdgcn_rcpf(fmaf(0.3275911f, z, 1.0f));
    const float e  = __expf(-z * z);
    float p = fmaf(t, 1.061405429f, -1.453152027f);
    p = fmaf(t, p, 1.421413741f);
    p = fmaf(t, p, -0.284496736f);
    p = fmaf(t, p, 0.254829592f);
    const float erfz = 1.0f - p * t * e;          // erf(|x|/sqrt(2))
    const float phi  = fmaf(copysignf(erfz, x), 0.5f, 0.5f);
    return x * phi;
}

#define RED_MAX32(v) do{ v = fmaxf(v, __shfl_xor(v,1));  v = fmaxf(v, __shfl_xor(v,2)); \
                         v = fmaxf(v, __shfl_xor(v,4));  v = fmaxf(v, __shfl_xor(v,8)); \
                         v = fmaxf(v, __shfl_xor(v,16)); }while(0)
#define RED_SUM32(v) do{ v += __shfl_xor(v,1);  v += __shfl_xor(v,2); \
                         v += __shfl_xor(v,4);  v += __shfl_xor(v,8); \
                         v += __shfl_xor(v,16); }while(0)

// ---- stats: per (b, head, seg) partial max / sumexp / kv over a 512-pos segment ----
__global__ __launch_bounds__(256) void stats_kernel(const float* __restrict__ h,
                                                    float* __restrict__ part){
    const int seg = blockIdx.x;
    const int hd  = blockIdx.y;
    const int b   = blockIdx.z;
    const int t   = threadIdx.x;
    const int d   = t >> 5;   // 0..7  (feature within head); wave-half owns one d
    const int j   = t & 31;   // 0..31 (position lane)

    __shared__ float tile[8][SEG_];   // 16 KB
    __shared__ float sm[8];

    const float* hb = h + (size_t)b * ((size_t)C_*L_) + (size_t)(hd*DH_)*L_ + (size_t)seg*SEG_;

    for (int f = t; f < 8*SEG_/4; f += 256){
        const int row = f >> 7;
        const int c4  = (f & 127) << 2;
        *(f32x4*)&tile[row][c4] = *(const f32x4*)&hb[(size_t)row*L_ + c4];
    }
    __syncthreads();

    float m = -INFINITY;
    #pragma unroll
    for (int i = 0; i < SEG_/32; i++) m = fmaxf(m, tile[d][j + 32*i]);
    RED_MAX32(m);
    if (j == 0) sm[d] = m;
    const float m_d = m;

    float s = 0.0f;
    float kv[8];
    #pragma unroll
    for (int e = 0; e < 8; e++) kv[e] = 0.0f;
    #pragma unroll
    for (int i = 0; i < SEG_/32; i++){
        const int k = j + 32*i;
        const float ek = __expf(tile[d][k] - m_d);
        s += ek;
        #pragma unroll
        for (int e = 0; e < 8; e++) kv[e] = fmaf(ek, tile[e][k], kv[e]);
    }
    RED_SUM32(s);
    #pragma unroll
    for (int e = 0; e < 8; e++){ RED_SUM32(kv[e]); }
    __syncthreads();

    float* po = part + (size_t)((b*H_ + hd)*S_ + seg) * 80;
    if (j == 0){
        po[8 + d] = s;
        #pragma unroll
        for (int e = 0; e < 8; e++) po[16 + d*8 + e] = kv[e];
    }
    if (t < 8) po[t] = sm[t];
}

// ---- per-position attention (fp32) + FC1/FC2 via f16 MFMA ----
// R4 post-mortem: latency-bound on the per-WG phase chain (occ ~32%, VALU 53%,
// BW 30%). This version cuts the chain:
//  * 2 sub-tiles (512 pos) per WG; BOTH h-tile loads issued in the prologue so
//    64 loads are in flight under weight-staging + merge; weights/merge
//    amortized 2x; 1024 WGs = exactly 4 WGs/CU of work (single round, no tail).
//  * hout stored DIRECTLY from D registers as float4 (lane owns 4 consecutive
//    positions x 1 channel) -- O16 transpose + its 4 barriers deleted. A wave's
//    16 stores are 16 full 64-B lines: all bytes used.
//  * no barrier between FC1 gelu-writeback and FC2 frag reads: both touch only
//    the wave's own 64 Ash rows; intra-wave lgkmcnt ordering suffices.
//  * head_kernel fused into LAST via done-counter (saves a launch + gap).
// OCCUPANCY NOTE (R1/R2): waves_per_eu(min>=5) forces spills; (3,4) proven
// spill-free. If WRITE_SIZE > 65536 KB next round, the h1 prefetch pushed regs
// over -- move it after attn(tile0).
// MFMA layouts (m89/m91-verified): A-frag lane holds A[m=lane&15][k=(lane>>4)*8+j];
// B-frag B[k][n=lane&15] (stored Bsh[n][k]); C/D col=lane&15, row=(lane>>4)*4+reg.
template<bool LAST>
__global__ __launch_bounds__(256)
__attribute__((amdgpu_waves_per_eu(3, 4)))
void block_kernel(const float* hin,
                  float* hout,
                  const float* __restrict__ part,
                  const float* __restrict__ W1,
                  const float* __restrict__ b1,
                  const float* __restrict__ W2,
                  const float* __restrict__ b2,
                  float* pooled,
                  unsigned* done_ctr,
                  const float* __restrict__ Wh,
                  const float* __restrict__ bh,
                  const float* __restrict__ gam,
                  const float* __restrict__ bet,
                  const float* __restrict__ mean,
                  const float* __restrict__ var,
                  const float* __restrict__ Wf,
                  const float* __restrict__ bf,
                  float* __restrict__ out){
    __shared__ __align__(16) f16_t Ash[256*AST];   // 20480 B
    __shared__ f16_t Bsh1[32*AST];                 // 2560 B
    __shared__ f16_t Bsh2[32*AST];                 // 2560 B
    __shared__ float sb1[32], sb2[32];
    __shared__ float kvsh[256];
    __shared__ float pool[32];
    __shared__ unsigned lastf;

    const int tid = threadIdx.x;
    const int b   = blockIdx.y;
    const int l0  = blockIdx.x * WTILE;
    const size_t base = (size_t)b * ((size_t)C_*L_);

    // ---- prologue: both tiles' h loads in flight; weights + merge hide them ----
    float h0[32], h1[32];
    #pragma unroll
    for (int c = 0; c < 32; c++) h0[c] = hin[base + (size_t)c*L_ + l0 + tid];
    #pragma unroll
    for (int c = 0; c < 32; c++) h1[c] = hin[base + (size_t)c*L_ + l0 + 256 + tid];

    for (int i = tid; i < 1024; i += 256){
        const int k = i >> 5, n = i & 31;
        Bsh1[n*AST + k] = (f16_t)W1[i];
        Bsh2[n*AST + k] = (f16_t)W2[i];
    }
    if (tid < 32){ sb1[tid] = b1[tid]; sb2[tid] = b2[tid]; }
    if (LAST && tid < 32) pool[tid] = 0.0f;

    // merge segment partials -> kvsh (one (head,d,e) per thread; part is L2-hot)
    {
        const int hh_t = tid >> 6;
        const int tt   = tid & 63;
        const int dd   = tt >> 3;
        const float* pp = part + (size_t)(b*H_ + hh_t) * S_ * 80;
        float M = -INFINITY;
        for (int s2 = 0; s2 < S_; s2++) M = fmaxf(M, pp[s2*80 + dd]);
        float ssum = 0.0f, kvs = 0.0f;
        for (int s2 = 0; s2 < S_; s2++){
            const float sc = __expf(pp[s2*80 + dd] - M);
            ssum = fmaf(pp[s2*80 + 8  + dd], sc, ssum);
            kvs  = fmaf(pp[s2*80 + 16 + tt], sc, kvs);
        }
        kvsh[tid] = kvs / ssum;
    }
    __syncthreads();   // kvsh + weights visible

    const int wv   = tid >> 6;
    const int lane = tid & 63;
    const int lr   = lane & 15;
    const int lk   = lane >> 4;
    const f32x4 zero = {0.f, 0.f, 0.f, 0.f};

    // attention for one tile -> Ash. preb: barrier before Ash overwrite
    // (needed when a previous tile's FC2 fragment reads may still be pending).
    auto attn_to_ash = [&](const float (&hh)[32], const bool preb){
        float attn[32];
        #pragma unroll
        for (int hd2 = 0; hd2 < 4; hd2++){
            float mq = hh[hd2*8];
            #pragma unroll
            for (int d2 = 1; d2 < 8; d2++) mq = fmaxf(mq, hh[hd2*8 + d2]);
            float es[8]; float qs = 0.f;
            #pragma unroll
            for (int d2 = 0; d2 < 8; d2++){ es[d2] = __expf(hh[hd2*8 + d2] - mq); qs += es[d2]; }
            const float inv = __builtin_amdgcn_rcpf(qs);
            #pragma unroll
            for (int e = 0; e < 8; e++){
                float acc = 0.f;
                #pragma unroll
                for (int d2 = 0; d2 < 8; d2++) acc += es[d2] * kvsh[hd2*64 + d2*8 + e];
                attn[hd2*8 + e] = acc * inv;
            }
        }
        if (preb) __syncthreads();
        #pragma unroll
        for (int k2 = 0; k2 < 32; k2 += 2){
            f16x2 pr = { (f16_t)attn[k2], (f16_t)attn[k2+1] };
            *(f16x2*)&Ash[tid*AST + k2] = pr;
        }
    };

    // FC1 -> gelu -> FC2 -> gelu -> store/pool for one tile
    auto fc_and_out = [&](const int lofs){
        f16x8 a[4], bw[2];
        f32x4 d[8];
        #pragma unroll
        for (int mt = 0; mt < 4; mt++)
            a[mt] = *(const f16x8*)&Ash[(wv*64 + mt*16 + lr)*AST + lk*8];
        #pragma unroll
        for (int nt = 0; nt < 2; nt++)
            bw[nt] = *(const f16x8*)&Bsh1[(nt*16 + lr)*AST + lk*8];
        #pragma unroll
        for (int nt = 0; nt < 2; nt++)
            #pragma unroll
            for (int mt = 0; mt < 4; mt++)
                d[nt*4+mt] = __builtin_amdgcn_mfma_f32_16x16x32_f16(a[mt], bw[nt], zero, 0, 0, 0);

        // bias + gelu + write back as A2 (wave-private rows: no barrier needed,
        // intra-wave ds ordering covers the cross-lane read-after-write)
        #pragma unroll
        for (int nt = 0; nt < 2; nt++){
            const float bias = sb1[nt*16 + lr];
            #pragma unroll
            for (int mt = 0; mt < 4; mt++)
                #pragma unroll
                for (int r = 0; r < 4; r++){
                    const float v = gelu_f(d[nt*4+mt][r] + bias);
                    Ash[(wv*64 + mt*16 + lk*4 + r)*AST + (nt*16 + lr)] = (f16_t)v;
                }
        }

        #pragma unroll
        for (int mt = 0; mt < 4; mt++)
            a[mt] = *(const f16x8*)&Ash[(wv*64 + mt*16 + lr)*AST + lk*8];
        #pragma unroll
        for (int nt = 0; nt < 2; nt++)
            bw[nt] = *(const f16x8*)&Bsh2[(nt*16 + lr)*AST + lk*8];
        #pragma unroll
        for (int nt = 0; nt < 2; nt++)
            #pragma unroll
            for (int mt = 0; mt < 4; mt++)
                d[nt*4+mt] = __builtin_amdgcn_mfma_f32_16x16x32_f16(a[mt], bw[nt], zero, 0, 0, 0);

        #pragma unroll
        for (int nt = 0; nt < 2; nt++){
            const float bias = sb2[nt*16 + lr];
            #pragma unroll
            for (int mt = 0; mt < 4; mt++)
                #pragma unroll
                for (int r = 0; r < 4; r++)
                    d[nt*4+mt][r] = gelu_f(d[nt*4+mt][r] + bias);
        }

        if (!LAST){
            // lane owns 4 consecutive positions of channel nt*16+lr -> float4
            #pragma unroll
            for (int nt = 0; nt < 2; nt++)
                #pragma unroll
                for (int mt = 0; mt < 4; mt++)
                    *(f32x4*)&hout[base + (size_t)(nt*16 + lr)*L_
                                   + l0 + lofs + wv*64 + mt*16 + lk*4] = d[nt*4+mt];
        } else {
            #pragma unroll
            for (int nt = 0; nt < 2; nt++){
                float ps = 0.f;
                #pragma unroll
                for (int mt = 0; mt < 4; mt++)
                    ps += d[nt*4+mt][0] + d[nt*4+mt][1] + d[nt*4+mt][2] + d[nt*4+mt][3];
                atomicAdd(&pool[nt*16 + lr], ps);
            }
        }
    };

    // tile 0
    attn_to_ash(h0, false);
    __syncthreads();
    fc_and_out(0);
    // tile 1 (barrier inside attn_to_ash orders Ash rewrite vs tile-0 FC2 reads)
    attn_to_ash(h1, true);
    __syncthreads();
    fc_and_out(256);

    if (LAST){
        __syncthreads();   // LDS pool atomics complete
        if (tid < 32){
            atomicAdd(&pooled[b*32 + tid], pool[tid]);
            __threadfence();   // release pooled before counter bump
        }
        __syncthreads();
        if (tid == 0){
            const unsigned old = atomicAdd(done_ctr, 1u);
            lastf = (old == 1023u) ? 1u : 0u;   // grid = 32 x 32 WGs
        }
        __syncthreads();
        if (lastf){
            // all other WGs' pooled adds happened-before our counter read
            __threadfence();   // acquire
            float* y2 = (float*)Ash;   // 4 KB scratch, Ash is dead
            const float invL = 1.0f / (float)L_;
            for (int i = tid; i < 1024; i += 256){
                const int bb = i >> 5, cc = i & 31;
                float acc = bh[cc];
                #pragma unroll
                for (int dd2 = 0; dd2 < 32; dd2++)
                    acc += (pooled[bb*32 + dd2] * invL) * Wh[dd2*32 + cc];
                acc = (acc - mean[cc]) * rsqrtf(var[cc] + 1e-5f) * gam[cc] + bet[cc];
                y2[i] = gelu_f(acc);
            }
            __syncthreads();
            for (int i = tid; i < B_*DOUT_; i += 256){
                const int b2 = i / DOUT_, j = i % DOUT_;
                float r = bf[j];
                #pragma unroll
                for (int c2 = 0; c2 < 32; c2++) r += y2[b2*32 + c2] * Wf[c2*DOUT_ + j];
                out[i] = r;
            }
        }
    }
}

extern "C" void kernel_launch(void* const* d_in, const int* in_sizes, int n_in,
                              void* d_out, int out_size, void* d_ws, size_t ws_size,
                              hipStream_t stream){
    (void)in_sizes; (void)n_in; (void)out_size; (void)ws_size;
    const float* x    = (const float*)d_in[0];
    const float* fW1  = (const float*)d_in[1];
    const float* fb1  = (const float*)d_in[2];
    const float* fW2  = (const float*)d_in[3];
    const float* fb2  = (const float*)d_in[4];
    const float* Wh   = (const float*)d_in[5];
    const float* bh   = (const float*)d_in[6];
    const float* gam  = (const float*)d_in[7];
    const float* bet  = (const float*)d_in[8];
    const float* mean = (const float*)d_in[9];
    const float* var  = (const float*)d_in[10];
    const float* Wf   = (const float*)d_in[11];
    const float* bf   = (const float*)d_in[12];
    float* out = (float*)d_out;

    float* hbuf    = (float*)d_ws;                          // B*C*L floats (64 MB)
    float* part    = hbuf + (size_t)B_*C_*L_;               // B*H*S_*80 (~1.3 MB)
    float* pooled  = part + (size_t)B_*H_*S_*80;            // B*C
    unsigned* done = (unsigned*)(pooled + B_*C_);           // 1 counter

    hipMemsetAsync(pooled, 0, (B_*C_ + 1)*sizeof(float), stream);

    dim3 sgrid(S_, H_, B_);
    dim3 bgrid(L_/WTILE, B_);

    // block 0 (input = x, output -> hbuf)
    stats_kernel<<<sgrid, 256, 0, stream>>>(x, part);
    block_kernel<false><<<bgrid, 256, 0, stream>>>(x, hbuf, part,
        fW1, fb1, fW2, fb2, nullptr, nullptr,
        nullptr, nullptr, nullptr, nullptr, nullptr, nullptr, nullptr, nullptr, nullptr);
    // block 1 (in-place on hbuf)
    stats_kernel<<<sgrid, 256, 0, stream>>>(hbuf, part);
    block_kernel<false><<<bgrid, 256, 0, stream>>>(hbuf, hbuf, part,
        fW1 + C_*C_, fb1 + C_, fW2 + C_*C_, fb2 + C_, nullptr, nullptr,
        nullptr, nullptr, nullptr, nullptr, nullptr, nullptr, nullptr, nullptr, nullptr);
    // block 2 (no h write; pooled reduce + fused head in last WG)
    stats_kernel<<<sgrid, 256, 0, stream>>>(hbuf, part);
    block_kernel<true><<<bgrid, 256, 0, stream>>>(hbuf, nullptr, part,
        fW1 + 2*C_*C_, fb1 + 2*C_, fW2 + 2*C_*C_, fb2 + 2*C_, pooled, done,
        Wh, bh, gam, bet, mean, var, Wf, bf, out);
}